// Round 1
// baseline (1414.063 us; speedup 1.0000x reference)
//
#include <hip/hip_runtime.h>

#define D 128
#define EPB 8

__device__ __forceinline__ unsigned enc_f(float f) {
    unsigned u = __float_as_uint(f);
    return (u & 0x80000000u) ? ~u : (u | 0x80000000u);
}
__device__ __forceinline__ float dec_f(unsigned u) {
    return (u & 0x80000000u) ? __uint_as_float(u ^ 0x80000000u) : __uint_as_float(~u);
}

__global__ void init_kernel(float* __restrict__ sum, float* __restrict__ sumsq,
                            unsigned* __restrict__ mxe, unsigned* __restrict__ mne,
                            int* __restrict__ cnt, int nNodes) {
    int i = blockIdx.x * blockDim.x + threadIdx.x;
    int total = nNodes * D;
    if (i < total) {
        sum[i] = 0.f;
        sumsq[i] = 0.f;
        mxe[i] = 0u;            // encodes -inf-ish floor
        mne[i] = 0xFFFFFFFFu;   // encodes +inf-ish ceiling
    }
    if (i < nNodes) cnt[i] = 0;
}

__global__ void qproj_kernel(const float* __restrict__ q, const float* __restrict__ Wq,
                             float* __restrict__ qp) {
    int node = blockIdx.x;
    int d = threadIdx.x;
    __shared__ float qs[D];
    qs[d] = q[node * D + d];
    __syncthreads();
    float acc = 0.f;
#pragma unroll 8
    for (int j = 0; j < D; ++j) acc = fmaf(qs[j], Wq[j * D + d], acc);
    qp[node * D + d] = acc;
}

__global__ void edge_kernel(const float* __restrict__ E, const float* __restrict__ R,
                            const float* __restrict__ qp,
                            const float* __restrict__ Wk, const float* __restrict__ Wv,
                            const float* __restrict__ deg,
                            const int* __restrict__ src, const int* __restrict__ rel,
                            const int* __restrict__ dst,
                            float* __restrict__ sum, float* __restrict__ sumsq,
                            unsigned* __restrict__ mxe, unsigned* __restrict__ mne,
                            int* __restrict__ cnt, int nE) {
    int d = threadIdx.x;   // 0..127
    int e0 = blockIdx.x * EPB;
    __shared__ float msg[EPB][D];
    __shared__ int sdst[EPB];
    __shared__ float sdeg[EPB];

#pragma unroll
    for (int e = 0; e < EPB; ++e) {
        int ei = e0 + e;
        if (ei < nE) {
            msg[e][d] = E[src[ei] * D + d] * R[rel[ei] * D + d];
        } else {
            msg[e][d] = 0.f;
        }
    }
    if (d < EPB) {
        int ei = e0 + d;
        sdst[d] = (ei < nE) ? dst[ei] : -1;
        sdeg[d] = (ei < nE) ? deg[ei] : 0.f;
    }
    __syncthreads();

    float kacc[EPB], vacc[EPB];
#pragma unroll
    for (int e = 0; e < EPB; ++e) { kacc[e] = 0.f; vacc[e] = 0.f; }

    for (int j = 0; j < D; ++j) {
        float wk = Wk[j * D + d];
        float wv = Wv[j * D + d];
#pragma unroll
        for (int e = 0; e < EPB; ++e) {
            float m = msg[e][j];   // LDS broadcast
            kacc[e] = fmaf(m, wk, kacc[e]);
            vacc[e] = fmaf(m, wv, vacc[e]);
        }
    }

#pragma unroll
    for (int e = 0; e < EPB; ++e) {
        int dn = sdst[e];
        if (dn < 0) continue;
        float qe = qp[dn * D + d];
        float p = qe * kacc[e];
        // reduce over 16-lane head groups (head = d/16)
        p += __shfl_xor(p, 1);
        p += __shfl_xor(p, 2);
        p += __shfl_xor(p, 4);
        p += __shfl_xor(p, 8);
        float alpha = p * 0.25f;               // / sqrt(16)
        float w = 1.f / (1.f + __expf(-alpha)); // sigmoid
        float x = w * vacc[e] * sdeg[e];

        atomicAdd(&sum[dn * D + d], x);
        atomicAdd(&sumsq[dn * D + d], x * x);
        atomicMax(&mxe[dn * D + d], enc_f(x));
        atomicMin(&mne[dn * D + d], enc_f(x));
        if (d == 0) atomicAdd(&cnt[dn], 1);
    }
}

__global__ void finalize_kernel(const float* __restrict__ sum, const float* __restrict__ sumsq,
                                const unsigned* __restrict__ mxe, const unsigned* __restrict__ mne,
                                const int* __restrict__ cnt, const float* __restrict__ Wo,
                                const float* __restrict__ q, const float* __restrict__ ln_g,
                                const float* __restrict__ ln_b, float* __restrict__ out) {
    int node = blockIdx.x;
    int d = threadIdx.x;   // 0..127
    int c = cnt[node];
    float s = sum[node * D + d];
    float sq = sumsq[node * D + d];
    float mean = (c > 0) ? s / (float)c : 0.f;
    float mx = (c > 0) ? dec_f(mxe[node * D + d]) : 0.f;
    float mn = (c > 0) ? dec_f(mne[node * D + d]) : 0.f;
    float sd = sqrtf(fmaxf(sq - s * s, 1e-8f));   // matches reference (raw sums)

    __shared__ float agg[4 * D];
    agg[d] = mean;
    agg[D + d] = mx;
    agg[2 * D + d] = mn;
    agg[3 * D + d] = sd;
    __syncthreads();

    float acc = 0.f;
#pragma unroll 8
    for (int j = 0; j < 4 * D; ++j) acc = fmaf(agg[j], Wo[j * D + d], acc);

    float h = acc + q[node * D + d];

    // LayerNorm over 128 (2 waves)
    __shared__ float red[4];
    float v = h;
#pragma unroll
    for (int off = 32; off > 0; off >>= 1) v += __shfl_down(v, off);
    if ((d & 63) == 0) red[d >> 6] = v;
    __syncthreads();
    float mu = (red[0] + red[1]) * (1.f / 128.f);
    float diff = h - mu;
    float v2 = diff * diff;
#pragma unroll
    for (int off = 32; off > 0; off >>= 1) v2 += __shfl_down(v2, off);
    if ((d & 63) == 0) red[2 + (d >> 6)] = v2;
    __syncthreads();
    float var = (red[2] + red[3]) * (1.f / 128.f);
    float r = rsqrtf(var + 1e-5f);
    out[node * D + d] = diff * r * ln_g[d] + ln_b[d];
}

extern "C" void kernel_launch(void* const* d_in, const int* in_sizes, int n_in,
                              void* d_out, int out_size, void* d_ws, size_t ws_size,
                              hipStream_t stream) {
    const float* q    = (const float*)d_in[0];
    const float* E    = (const float*)d_in[1];
    const float* R    = (const float*)d_in[2];
    const float* Wq   = (const float*)d_in[3];
    const float* Wk   = (const float*)d_in[4];
    const float* Wv   = (const float*)d_in[5];
    const float* Wo   = (const float*)d_in[6];
    const float* ln_g = (const float*)d_in[7];
    const float* ln_b = (const float*)d_in[8];
    const float* deg  = (const float*)d_in[9];
    const int* src    = (const int*)d_in[10];
    const int* rel    = (const int*)d_in[11];
    const int* dst    = (const int*)d_in[12];
    int nNodes = in_sizes[0] / D;
    int nEdges = in_sizes[10];
    float* out = (float*)d_out;

    char* w = (char*)d_ws;
    size_t nd = (size_t)nNodes * D;
    float* qp     = (float*)w;  w += nd * 4;
    float* sum    = (float*)w;  w += nd * 4;
    float* sumsq  = (float*)w;  w += nd * 4;
    unsigned* mxe = (unsigned*)w; w += nd * 4;
    unsigned* mne = (unsigned*)w; w += nd * 4;
    int* cnt      = (int*)w;    w += (size_t)nNodes * 4;

    init_kernel<<<(int)((nd + 255) / 256), 256, 0, stream>>>(sum, sumsq, mxe, mne, cnt, nNodes);
    qproj_kernel<<<nNodes, D, 0, stream>>>(q, Wq, qp);
    edge_kernel<<<(nEdges + EPB - 1) / EPB, D, 0, stream>>>(E, R, qp, Wk, Wv, deg, src, rel, dst,
                                                            sum, sumsq, mxe, mne, cnt, nEdges);
    finalize_kernel<<<nNodes, D, 0, stream>>>(sum, sumsq, mxe, mne, cnt, Wo, q, ln_g, ln_b, out);
}

// Round 3
// 1327.057 us; speedup vs baseline: 1.0656x; 1.0656x over previous
//
#include <hip/hip_runtime.h>

#define D 128
#define FLT_BIG 3.402823466e+38f

__device__ __forceinline__ unsigned enc_f(float f) {
    unsigned u = __float_as_uint(f);
    return (u & 0x80000000u) ? ~u : (u | 0x80000000u);
}
__device__ __forceinline__ float dec_f(unsigned u) {
    return (u & 0x80000000u) ? __uint_as_float(u ^ 0x80000000u) : __uint_as_float(~u);
}
__device__ __forceinline__ unsigned short f2bf(float f) {
    unsigned u = __float_as_uint(f);
    unsigned r = (u + 0x7FFFu + ((u >> 16) & 1u)) >> 16;
    return (unsigned short)r;
}
__device__ __forceinline__ float bf2f(unsigned short s) {
    return __uint_as_float(((unsigned)s) << 16);
}

// ---------------- init: accumulators + counters ----------------

__global__ void init_kernel(float* __restrict__ sum, float* __restrict__ sumsq,
                            unsigned* __restrict__ mxe, unsigned* __restrict__ mne,
                            int* __restrict__ cnt, int* __restrict__ fill, int nNodes) {
    int i = blockIdx.x * blockDim.x + threadIdx.x;
    int total = nNodes * D;
    if (i < total) {
        sum[i] = 0.f;
        sumsq[i] = 0.f;
        mxe[i] = 0u;            // below any encoded float
        mne[i] = 0xFFFFFFFFu;   // above any encoded float
    }
    if (i < nNodes) { cnt[i] = 0; fill[i] = 0; }
}

// ---------------- CSR build ----------------

__global__ void hist_kernel(const int* __restrict__ dst, int* __restrict__ cnt, int nE) {
    int i = blockIdx.x * blockDim.x + threadIdx.x;
    if (i < nE) atomicAdd(&cnt[dst[i]], 1);
}

__global__ void scanA_kernel(const int* __restrict__ cnt, int* __restrict__ chunksum, int n) {
    __shared__ int sm[256];
    int t = threadIdx.x;
    int i = blockIdx.x * 256 + t;
    sm[t] = (i < n) ? cnt[i] : 0;
    __syncthreads();
    for (int s = 128; s > 0; s >>= 1) {
        if (t < s) sm[t] += sm[t + s];
        __syncthreads();
    }
    if (t == 0) chunksum[blockIdx.x] = sm[0];
}

__global__ void scanB_kernel(const int* __restrict__ chunksum, int* __restrict__ chunkoff, int nc) {
    __shared__ int sm[256];
    int t = threadIdx.x;
    int v = (t < nc) ? chunksum[t] : 0;
    sm[t] = v;
    __syncthreads();
    for (int s = 1; s < 256; s <<= 1) {
        int add = (t >= s) ? sm[t - s] : 0;
        __syncthreads();
        sm[t] += add;
        __syncthreads();
    }
    if (t < nc) chunkoff[t] = sm[t] - v;   // exclusive prefix of chunk sums
}

__global__ void scanC_kernel(const int* __restrict__ cnt, const int* __restrict__ chunkoff,
                             int* __restrict__ off, int n) {
    __shared__ int sm[256];
    int t = threadIdx.x;
    int i = blockIdx.x * 256 + t;
    int v = (i < n) ? cnt[i] : 0;
    sm[t] = v;
    __syncthreads();
    for (int s = 1; s < 256; s <<= 1) {
        int add = (t >= s) ? sm[t - s] : 0;
        __syncthreads();
        sm[t] += add;
        __syncthreads();
    }
    if (i < n) off[i] = chunkoff[blockIdx.x] + sm[t] - v;
}

__global__ void scatter_kernel(const int* __restrict__ dst, const int* __restrict__ off,
                               int* __restrict__ fill, int* __restrict__ perm, int nE) {
    int i = blockIdx.x * blockDim.x + threadIdx.x;
    if (i < nE) {
        int d = dst[i];
        int p = off[d] + atomicAdd(&fill[d], 1);
        perm[p] = i;
    }
}

// ---------------- q projection: 4 nodes / 128-thread block, bf16 output ----------------

__global__ void qproj_kernel(const float* __restrict__ q, const float* __restrict__ Wq,
                             unsigned short* __restrict__ qp) {
    int t = threadIdx.x;
    int nbase = blockIdx.x * 4;
    __shared__ float qs[4][D];
#pragma unroll
    for (int r = 0; r < 4; ++r) qs[r][t] = q[(size_t)(nbase + r) * D + t];
    __syncthreads();
    int sub = t >> 5;
    int c4 = (t & 31) << 2;
    float ax = 0.f, ay = 0.f, az = 0.f, aw = 0.f;
    const float* Wp = Wq + c4;
#pragma unroll 4
    for (int j = 0; j < D; ++j) {
        float m = qs[sub][j];
        float4 w4 = *(const float4*)(Wp + (size_t)j * D);
        ax = fmaf(m, w4.x, ax); ay = fmaf(m, w4.y, ay);
        az = fmaf(m, w4.z, az); aw = fmaf(m, w4.w, aw);
    }
    ushort4 o;
    o.x = f2bf(ax); o.y = f2bf(ay); o.z = f2bf(az); o.w = f2bf(aw);
    *(ushort4*)(qp + (size_t)(nbase + sub) * D + c4) = o;
}

// ---------------- edge compute + segmented scatter ----------------

__device__ __forceinline__ void flush_stats(float* __restrict__ sum, float* __restrict__ sumsq,
                                            unsigned* __restrict__ mxe, unsigned* __restrict__ mne,
                                            int node, int c4,
                                            float4 s, float4 q, float4 mx, float4 mn) {
    size_t b = (size_t)node * D + c4;
    atomicAdd(&sum[b + 0], s.x); atomicAdd(&sum[b + 1], s.y);
    atomicAdd(&sum[b + 2], s.z); atomicAdd(&sum[b + 3], s.w);
    atomicAdd(&sumsq[b + 0], q.x); atomicAdd(&sumsq[b + 1], q.y);
    atomicAdd(&sumsq[b + 2], q.z); atomicAdd(&sumsq[b + 3], q.w);
    atomicMax(&mxe[b + 0], enc_f(mx.x)); atomicMax(&mxe[b + 1], enc_f(mx.y));
    atomicMax(&mxe[b + 2], enc_f(mx.z)); atomicMax(&mxe[b + 3], enc_f(mx.w));
    atomicMin(&mne[b + 0], enc_f(mn.x)); atomicMin(&mne[b + 1], enc_f(mn.y));
    atomicMin(&mne[b + 2], enc_f(mn.z)); atomicMin(&mne[b + 3], enc_f(mn.w));
}

__global__ __launch_bounds__(256) void edge_kernel(
        const float* __restrict__ E, const float* __restrict__ R,
        const unsigned short* __restrict__ qp,
        const float* __restrict__ Wk, const float* __restrict__ Wv,
        const float* __restrict__ deg,
        const int* __restrict__ src, const int* __restrict__ rel,
        const int* __restrict__ dst, const int* __restrict__ perm,
        float* __restrict__ sum, float* __restrict__ sumsq,
        unsigned* __restrict__ mxe, unsigned* __restrict__ mne, int nE) {
    int t = threadIdx.x;
    int wvi = t >> 6;
    int l = t & 63;
    int e0 = blockIdx.x * 32 + wvi * 8;
    __shared__ float msg[32][D];

    int pe[8], dn[8];
#pragma unroll
    for (int e = 0; e < 8; ++e) pe[e] = perm[e0 + e];
#pragma unroll
    for (int e = 0; e < 8; ++e) dn[e] = dst[pe[e]];

#pragma unroll
    for (int e = 0; e < 8; ++e) {
        int sr = src[pe[e]], rr = rel[pe[e]];
        float2 ev = *(const float2*)(E + (size_t)sr * D + 2 * l);
        float2 rv = *(const float2*)(R + (size_t)rr * D + 2 * l);
        float2 m2; m2.x = ev.x * rv.x; m2.y = ev.y * rv.y;
        *(float2*)(&msg[wvi * 8 + e][2 * l]) = m2;
    }
    __syncthreads();

    int half = l >> 5;
    int c4 = (l & 31) << 2;
    const float* Wp = (half ? Wv : Wk) + c4;
    float4 acc[8];
#pragma unroll
    for (int e = 0; e < 8; ++e) { acc[e].x = 0.f; acc[e].y = 0.f; acc[e].z = 0.f; acc[e].w = 0.f; }

    const float* mrow = &msg[wvi * 8][0];
    for (int j4 = 0; j4 < 32; ++j4) {
        int j = j4 * 4;
        float4 w0 = *(const float4*)(Wp + (size_t)(j + 0) * D);
        float4 w1 = *(const float4*)(Wp + (size_t)(j + 1) * D);
        float4 w2 = *(const float4*)(Wp + (size_t)(j + 2) * D);
        float4 w3 = *(const float4*)(Wp + (size_t)(j + 3) * D);
#pragma unroll
        for (int e = 0; e < 8; ++e) {
            float4 m = *(const float4*)(mrow + e * D + j);
            acc[e].x = fmaf(m.x, w0.x, acc[e].x); acc[e].y = fmaf(m.x, w0.y, acc[e].y);
            acc[e].z = fmaf(m.x, w0.z, acc[e].z); acc[e].w = fmaf(m.x, w0.w, acc[e].w);
            acc[e].x = fmaf(m.y, w1.x, acc[e].x); acc[e].y = fmaf(m.y, w1.y, acc[e].y);
            acc[e].z = fmaf(m.y, w1.z, acc[e].z); acc[e].w = fmaf(m.y, w1.w, acc[e].w);
            acc[e].x = fmaf(m.z, w2.x, acc[e].x); acc[e].y = fmaf(m.z, w2.y, acc[e].y);
            acc[e].z = fmaf(m.z, w2.z, acc[e].z); acc[e].w = fmaf(m.z, w2.w, acc[e].w);
            acc[e].x = fmaf(m.w, w3.x, acc[e].x); acc[e].y = fmaf(m.w, w3.y, acc[e].y);
            acc[e].z = fmaf(m.w, w3.z, acc[e].z); acc[e].w = fmaf(m.w, w3.w, acc[e].w);
        }
    }

    float wgt[8];
#pragma unroll
    for (int e = 0; e < 8; ++e) {
        float w = 0.f;
        if (half == 0) {
            ushort4 qb = *(const ushort4*)(qp + (size_t)dn[e] * D + c4);
            float p = bf2f(qb.x) * acc[e].x + bf2f(qb.y) * acc[e].y
                    + bf2f(qb.z) * acc[e].z + bf2f(qb.w) * acc[e].w;
            p += __shfl_xor(p, 1);
            p += __shfl_xor(p, 2);      // 4 lanes = one 16-dim head
            float alpha = p * 0.25f;    // / sqrt(16)
            w = 1.f / (1.f + __expf(-alpha));
        }
        wgt[e] = __shfl_xor(w, 32);
    }

    if (half == 1) {
        float f0 = wgt[0] * deg[pe[0]];
        float4 x;
        x.x = acc[0].x * f0; x.y = acc[0].y * f0; x.z = acc[0].z * f0; x.w = acc[0].w * f0;
        float4 s = x;
        float4 q2; q2.x = x.x * x.x; q2.y = x.y * x.y; q2.z = x.z * x.z; q2.w = x.w * x.w;
        float4 mx = x, mn = x;
        int run = dn[0];
#pragma unroll
        for (int e = 1; e < 8; ++e) {
            float f = wgt[e] * deg[pe[e]];
            x.x = acc[e].x * f; x.y = acc[e].y * f; x.z = acc[e].z * f; x.w = acc[e].w * f;
            if (dn[e] == run) {
                s.x += x.x; s.y += x.y; s.z += x.z; s.w += x.w;
                q2.x = fmaf(x.x, x.x, q2.x); q2.y = fmaf(x.y, x.y, q2.y);
                q2.z = fmaf(x.z, x.z, q2.z); q2.w = fmaf(x.w, x.w, q2.w);
                mx.x = fmaxf(mx.x, x.x); mx.y = fmaxf(mx.y, x.y);
                mx.z = fmaxf(mx.z, x.z); mx.w = fmaxf(mx.w, x.w);
                mn.x = fminf(mn.x, x.x); mn.y = fminf(mn.y, x.y);
                mn.z = fminf(mn.z, x.z); mn.w = fminf(mn.w, x.w);
            } else {
                flush_stats(sum, sumsq, mxe, mne, run, c4, s, q2, mx, mn);
                run = dn[e];
                s = x;
                q2.x = x.x * x.x; q2.y = x.y * x.y; q2.z = x.z * x.z; q2.w = x.w * x.w;
                mx = x; mn = x;
            }
        }
        flush_stats(sum, sumsq, mxe, mne, run, c4, s, q2, mx, mn);
    }
}

// ---------------- finalize: stats -> PNA -> Wo -> residual -> LN, 8 nodes/block ----------------

__global__ __launch_bounds__(256) void finalize_kernel(
        const float* __restrict__ sum, const float* __restrict__ sumsq,
        const unsigned* __restrict__ mxe, const unsigned* __restrict__ mne,
        const int* __restrict__ cnt, const float* __restrict__ Wo,
        const float* __restrict__ q, const float* __restrict__ ln_g,
        const float* __restrict__ ln_b, float* __restrict__ out, int nNodes) {
    int t = threadIdx.x;
    int sub = t >> 5;
    int c4 = (t & 31) << 2;
    int node = blockIdx.x * 8 + sub;
    size_t b = (size_t)node * D + c4;

    int c = cnt[node];
    float4 s = *(const float4*)(sum + b);
    float4 sq = *(const float4*)(sumsq + b);
    uint4 mxu = *(const uint4*)(mxe + b);
    uint4 mnu = *(const uint4*)(mne + b);
    float invc = (c > 0) ? 1.f / (float)c : 0.f;
    float4 mean; mean.x = s.x * invc; mean.y = s.y * invc; mean.z = s.z * invc; mean.w = s.w * invc;
    float4 mx, mn;
    if (c > 0) {
        mx.x = dec_f(mxu.x); mx.y = dec_f(mxu.y); mx.z = dec_f(mxu.z); mx.w = dec_f(mxu.w);
        mn.x = dec_f(mnu.x); mn.y = dec_f(mnu.y); mn.z = dec_f(mnu.z); mn.w = dec_f(mnu.w);
    } else {
        mx.x = mx.y = mx.z = mx.w = 0.f;
        mn.x = mn.y = mn.z = mn.w = 0.f;
    }
    float4 sd;
    sd.x = sqrtf(fmaxf(sq.x - s.x * s.x, 1e-8f));
    sd.y = sqrtf(fmaxf(sq.y - s.y * s.y, 1e-8f));
    sd.z = sqrtf(fmaxf(sq.z - s.z * s.z, 1e-8f));
    sd.w = sqrtf(fmaxf(sq.w - s.w * s.w, 1e-8f));

    __shared__ float agg[8][4 * D];
    *(float4*)(&agg[sub][0 * D + c4]) = mean;
    *(float4*)(&agg[sub][1 * D + c4]) = mx;
    *(float4*)(&agg[sub][2 * D + c4]) = mn;
    *(float4*)(&agg[sub][3 * D + c4]) = sd;
    __syncthreads();

    float ax = 0.f, ay = 0.f, az = 0.f, aw = 0.f;
    const float* arow = agg[sub];
    const float* Wp = Wo + c4;
    for (int j4 = 0; j4 < 128; ++j4) {
        float4 m = *(const float4*)(arow + j4 * 4);
        float4 w0 = *(const float4*)(Wp + (size_t)(j4 * 4 + 0) * D);
        float4 w1 = *(const float4*)(Wp + (size_t)(j4 * 4 + 1) * D);
        float4 w2 = *(const float4*)(Wp + (size_t)(j4 * 4 + 2) * D);
        float4 w3 = *(const float4*)(Wp + (size_t)(j4 * 4 + 3) * D);
        ax = fmaf(m.x, w0.x, ax); ay = fmaf(m.x, w0.y, ay); az = fmaf(m.x, w0.z, az); aw = fmaf(m.x, w0.w, aw);
        ax = fmaf(m.y, w1.x, ax); ay = fmaf(m.y, w1.y, ay); az = fmaf(m.y, w1.z, az); aw = fmaf(m.y, w1.w, aw);
        ax = fmaf(m.z, w2.x, ax); ay = fmaf(m.z, w2.y, ay); az = fmaf(m.z, w2.z, az); aw = fmaf(m.z, w2.w, aw);
        ax = fmaf(m.w, w3.x, ax); ay = fmaf(m.w, w3.y, ay); az = fmaf(m.w, w3.z, az); aw = fmaf(m.w, w3.w, aw);
    }

    float4 qv = *(const float4*)(q + (size_t)node * D + c4);
    float hx = ax + qv.x, hy = ay + qv.y, hz = az + qv.z, hw = aw + qv.w;

    float part = hx + hy + hz + hw;
    part += __shfl_xor(part, 1);
    part += __shfl_xor(part, 2);
    part += __shfl_xor(part, 4);
    part += __shfl_xor(part, 8);
    part += __shfl_xor(part, 16);
    float mu = part * (1.f / 128.f);
    float dx = hx - mu, dy = hy - mu, dz = hz - mu, dw = hw - mu;
    float p2 = dx * dx + dy * dy + dz * dz + dw * dw;
    p2 += __shfl_xor(p2, 1);
    p2 += __shfl_xor(p2, 2);
    p2 += __shfl_xor(p2, 4);
    p2 += __shfl_xor(p2, 8);
    p2 += __shfl_xor(p2, 16);
    float var = p2 * (1.f / 128.f);
    float r = rsqrtf(var + 1e-5f);

    float4 gv = *(const float4*)(ln_g + c4);
    float4 bv = *(const float4*)(ln_b + c4);
    float4 ov;
    ov.x = dx * r * gv.x + bv.x;
    ov.y = dy * r * gv.y + bv.y;
    ov.z = dz * r * gv.z + bv.z;
    ov.w = dw * r * gv.w + bv.w;
    *(float4*)(out + (size_t)node * D + c4) = ov;
}

// ---------------- launch ----------------

extern "C" void kernel_launch(void* const* d_in, const int* in_sizes, int n_in,
                              void* d_out, int out_size, void* d_ws, size_t ws_size,
                              hipStream_t stream) {
    const float* q    = (const float*)d_in[0];
    const float* E    = (const float*)d_in[1];
    const float* R    = (const float*)d_in[2];
    const float* Wq   = (const float*)d_in[3];
    const float* Wk   = (const float*)d_in[4];
    const float* Wv   = (const float*)d_in[5];
    const float* Wo   = (const float*)d_in[6];
    const float* ln_g = (const float*)d_in[7];
    const float* ln_b = (const float*)d_in[8];
    const float* deg  = (const float*)d_in[9];
    const int* src    = (const int*)d_in[10];
    const int* rel    = (const int*)d_in[11];
    const int* dst    = (const int*)d_in[12];
    int nNodes = in_sizes[0] / D;   // 50000
    int nEdges = in_sizes[10];      // 500000
    float* out = (float*)d_out;

    char* w = (char*)d_ws;
    size_t nd = (size_t)nNodes * D;
    float* sum    = (float*)w;               w += nd * 4;
    float* sumsq  = (float*)w;               w += nd * 4;
    unsigned* mxe = (unsigned*)w;            w += nd * 4;
    unsigned* mne = (unsigned*)w;            w += nd * 4;
    unsigned short* qp = (unsigned short*)w; w += nd * 2;
    int* cnt      = (int*)w;                 w += (size_t)nNodes * 4;
    int* off      = (int*)w;                 w += (size_t)nNodes * 4;
    int* fill     = (int*)w;                 w += (size_t)nNodes * 4;
    int* perm     = (int*)w;                 w += (size_t)nEdges * 4;
    int* chunksum = (int*)w;                 w += 256 * 4;
    int* chunkoff = (int*)w;                 w += 256 * 4;
    // total ~117.8 MB (< 128.4 MB used successfully in R1)

    int nChunks = (nNodes + 255) / 256;   // 196

    init_kernel<<<(int)((nd + 255) / 256), 256, 0, stream>>>(sum, sumsq, mxe, mne, cnt, fill, nNodes);
    hist_kernel<<<(nEdges + 255) / 256, 256, 0, stream>>>(dst, cnt, nEdges);
    scanA_kernel<<<nChunks, 256, 0, stream>>>(cnt, chunksum, nNodes);
    scanB_kernel<<<1, 256, 0, stream>>>(chunksum, chunkoff, nChunks);
    scanC_kernel<<<nChunks, 256, 0, stream>>>(cnt, chunkoff, off, nNodes);
    scatter_kernel<<<(nEdges + 255) / 256, 256, 0, stream>>>(dst, off, fill, perm, nEdges);

    qproj_kernel<<<nNodes / 4, 128, 0, stream>>>(q, Wq, qp);
    edge_kernel<<<nEdges / 32, 256, 0, stream>>>(E, R, qp, Wk, Wv, deg, src, rel, dst, perm,
                                                 sum, sumsq, mxe, mne, nEdges);
    finalize_kernel<<<nNodes / 8, 256, 0, stream>>>(sum, sumsq, mxe, mne, cnt, Wo, q,
                                                    ln_g, ln_b, out, nNodes);
}

// Round 4
// 546.096 us; speedup vs baseline: 2.5894x; 2.4301x over previous
//
#include <hip/hip_runtime.h>

#define D 128

typedef __attribute__((ext_vector_type(8))) short short8;
typedef __attribute__((ext_vector_type(4))) float floatx4;

union __align__(16) U8 { unsigned short u[8]; short8 v; };

__device__ __forceinline__ unsigned enc_f(float f) {
    unsigned u = __float_as_uint(f);
    return (u & 0x80000000u) ? ~u : (u | 0x80000000u);
}
__device__ __forceinline__ float dec_f(unsigned u) {
    return (u & 0x80000000u) ? __uint_as_float(u ^ 0x80000000u) : __uint_as_float(~u);
}
__device__ __forceinline__ unsigned short f2bf(float f) {
    unsigned u = __float_as_uint(f);
    unsigned r = (u + 0x7FFFu + ((u >> 16) & 1u)) >> 16;
    return (unsigned short)r;
}
__device__ __forceinline__ float bf2f(unsigned short s) {
    return __uint_as_float(((unsigned)s) << 16);
}

// ---------------- init ----------------

__global__ void init_kernel(float* __restrict__ sum, float* __restrict__ sumsq,
                            unsigned* __restrict__ mxe, unsigned* __restrict__ mne,
                            int* __restrict__ cnt, int* __restrict__ fill, int nNodes) {
    int i = blockIdx.x * blockDim.x + threadIdx.x;
    int total = nNodes * D;
    if (i < total) {
        sum[i] = 0.f;
        sumsq[i] = 0.f;
        mxe[i] = 0u;
        mne[i] = 0xFFFFFFFFu;
    }
    if (i < nNodes) { cnt[i] = 0; fill[i] = 0; }
}

// ---------------- CSR build ----------------

__global__ void hist_kernel(const int* __restrict__ dst, int* __restrict__ cnt, int nE) {
    int i = blockIdx.x * blockDim.x + threadIdx.x;
    if (i < nE) atomicAdd(&cnt[dst[i]], 1);
}

__global__ void scanA_kernel(const int* __restrict__ cnt, int* __restrict__ chunksum, int n) {
    __shared__ int sm[256];
    int t = threadIdx.x;
    int i = blockIdx.x * 256 + t;
    sm[t] = (i < n) ? cnt[i] : 0;
    __syncthreads();
    for (int s = 128; s > 0; s >>= 1) {
        if (t < s) sm[t] += sm[t + s];
        __syncthreads();
    }
    if (t == 0) chunksum[blockIdx.x] = sm[0];
}

__global__ void scanB_kernel(const int* __restrict__ chunksum, int* __restrict__ chunkoff, int nc) {
    __shared__ int sm[256];
    int t = threadIdx.x;
    int v = (t < nc) ? chunksum[t] : 0;
    sm[t] = v;
    __syncthreads();
    for (int s = 1; s < 256; s <<= 1) {
        int add = (t >= s) ? sm[t - s] : 0;
        __syncthreads();
        sm[t] += add;
        __syncthreads();
    }
    if (t < nc) chunkoff[t] = sm[t] - v;
}

__global__ void scanC_kernel(const int* __restrict__ cnt, const int* __restrict__ chunkoff,
                             int* __restrict__ off, int n) {
    __shared__ int sm[256];
    int t = threadIdx.x;
    int i = blockIdx.x * 256 + t;
    int v = (i < n) ? cnt[i] : 0;
    sm[t] = v;
    __syncthreads();
    for (int s = 1; s < 256; s <<= 1) {
        int add = (t >= s) ? sm[t - s] : 0;
        __syncthreads();
        sm[t] += add;
        __syncthreads();
    }
    if (i < n) off[i] = chunkoff[blockIdx.x] + sm[t] - v;
}

__global__ void scatter_kernel(const int* __restrict__ dst, const int* __restrict__ off,
                               int* __restrict__ fill, int* __restrict__ perm, int nE) {
    int i = blockIdx.x * blockDim.x + threadIdx.x;
    if (i < nE) {
        int d = dst[i];
        int p = off[d] + atomicAdd(&fill[d], 1);
        perm[p] = i;
    }
}

// ---------------- pack W into MFMA B-fragment order ----------------
// B-frag element j of lane l for (nt, ks): W[k = ks*32 + (l>>4)*8 + j][col = nt*16 + (l&15)]
// stored at ((nt*(K/32) + ks)*64 + l)*8 + j

__global__ void pack_kernel(const float* __restrict__ W0, const float* __restrict__ W1,
                            int Kdim, unsigned short* __restrict__ hi,
                            unsigned short* __restrict__ lo) {
    int ksn = Kdim >> 5;
    int nt = blockIdx.x / ksn;
    int ks = blockIdx.x % ksn;
    int l = threadIdx.x;
    int c = nt * 16 + (l & 15);
    const float* Wsrc = (c < 128) ? W0 : W1;
    int cc = c & 127;
    int kbase = ks * 32 + (l >> 4) * 8;
    size_t o = ((size_t)blockIdx.x * 64 + l) * 8;
#pragma unroll
    for (int j = 0; j < 8; ++j) {
        float w = Wsrc[(size_t)(kbase + j) * 128 + cc];
        unsigned short h = f2bf(w);
        hi[o + j] = h;
        if (lo) lo[o + j] = f2bf(w - bf2f(h));
    }
}

// ---------------- qproj via MFMA: 64 nodes / 256-thread block ----------------

__global__ __launch_bounds__(256, 2) void qproj_mfma(
        const float* __restrict__ q,
        const unsigned short* __restrict__ Bhi, const unsigned short* __restrict__ Blo,
        unsigned short* __restrict__ qp, int nNodes) {
    __shared__ __align__(16) unsigned short qhi[64][128];
    __shared__ __align__(16) unsigned short qlo[64][128];
    int t = threadIdx.x;
    int n0 = blockIdx.x * 64;
    {
        int e = t >> 2, sub = t & 3;
        int node = n0 + e;
        for (int cc = 0; cc < 4; ++cc) {
            int chunk = sub * 4 + cc;
            U8 H, L;
            if (node < nNodes) {
                const float* srcp = q + (size_t)node * 128 + chunk * 8;
                float4 v0 = *(const float4*)(srcp);
                float4 v1 = *(const float4*)(srcp + 4);
                float vv[8] = {v0.x, v0.y, v0.z, v0.w, v1.x, v1.y, v1.z, v1.w};
#pragma unroll
                for (int j = 0; j < 8; ++j) {
                    unsigned short h = f2bf(vv[j]);
                    H.u[j] = h; L.u[j] = f2bf(vv[j] - bf2f(h));
                }
            } else {
#pragma unroll
                for (int j = 0; j < 8; ++j) { H.u[j] = 0; L.u[j] = 0; }
            }
            int sc = chunk ^ (e & 7);
            *reinterpret_cast<short8*>(&qhi[e][sc * 8]) = H.v;
            *reinterpret_cast<short8*>(&qlo[e][sc * 8]) = L.v;
        }
    }
    __syncthreads();
    int w = t >> 6, l = t & 63;
    int lrow = l & 15, lk = l >> 4;
    floatx4 acc[4][2];
#pragma unroll
    for (int mt = 0; mt < 4; ++mt)
#pragma unroll
        for (int n = 0; n < 2; ++n) acc[mt][n] = (floatx4){0.f, 0.f, 0.f, 0.f};
    for (int ks = 0; ks < 4; ++ks) {
        short8 ah[4], al[4];
#pragma unroll
        for (int mt = 0; mt < 4; ++mt) {
            int row = mt * 16 + lrow;
            int sc = (ks * 4 + lk) ^ (row & 7);
            ah[mt] = *reinterpret_cast<const short8*>(&qhi[row][sc * 8]);
            al[mt] = *reinterpret_cast<const short8*>(&qlo[row][sc * 8]);
        }
#pragma unroll
        for (int ntl = 0; ntl < 2; ++ntl) {
            int ntg = w * 2 + ntl;
            size_t bo = ((size_t)(ntg * 4 + ks) * 64 + l) * 8;
            short8 bh = *reinterpret_cast<const short8*>(Bhi + bo);
            short8 bl = *reinterpret_cast<const short8*>(Blo + bo);
#pragma unroll
            for (int mt = 0; mt < 4; ++mt) {
                acc[mt][ntl] = __builtin_amdgcn_mfma_f32_16x16x32_bf16(ah[mt], bh, acc[mt][ntl], 0, 0, 0);
                acc[mt][ntl] = __builtin_amdgcn_mfma_f32_16x16x32_bf16(al[mt], bh, acc[mt][ntl], 0, 0, 0);
                acc[mt][ntl] = __builtin_amdgcn_mfma_f32_16x16x32_bf16(ah[mt], bl, acc[mt][ntl], 0, 0, 0);
            }
        }
    }
#pragma unroll
    for (int mt = 0; mt < 4; ++mt)
#pragma unroll
        for (int ntl = 0; ntl < 2; ++ntl) {
            int col = (w * 2 + ntl) * 16 + lrow;
#pragma unroll
            for (int r = 0; r < 4; ++r) {
                int row = mt * 16 + lk * 4 + r;
                int node = n0 + row;
                if (node < nNodes) qp[(size_t)node * 128 + col] = f2bf(acc[mt][ntl][r]);
            }
        }
}

// ---------------- edge kernel via MFMA: 64 sorted edges / 256-thread block ----------------

__device__ __forceinline__ void flush1(float* __restrict__ sum, float* __restrict__ sumsq,
                                       unsigned* __restrict__ mxe, unsigned* __restrict__ mne,
                                       int node, int col, float s, float q2, float mx, float mn) {
    size_t b = (size_t)node * 128 + col;
    atomicAdd(&sum[b], s);
    atomicAdd(&sumsq[b], q2);
    atomicMax(&mxe[b], enc_f(mx));
    atomicMin(&mne[b], enc_f(mn));
}

__global__ __launch_bounds__(256, 2) void edge_mfma(
        const float* __restrict__ E, const float* __restrict__ R,
        const unsigned short* __restrict__ qp,
        const unsigned short* __restrict__ Bhi, const unsigned short* __restrict__ Blo,
        const float* __restrict__ deg,
        const int* __restrict__ src, const int* __restrict__ rel,
        const int* __restrict__ dst, const int* __restrict__ perm,
        float* __restrict__ sum, float* __restrict__ sumsq,
        unsigned* __restrict__ mxe, unsigned* __restrict__ mne, int nE) {

    __shared__ __align__(16) unsigned short msgb[2][64][128];  // 32KB; reused as V fp32 [64][128]
    __shared__ __align__(16) unsigned short Kb[64][128];       // 16KB
    __shared__ float alph[64][8];
    __shared__ int sdst[64];
    __shared__ float sdegs[64];

    int t = threadIdx.x;
    int e0 = blockIdx.x * 64;

    if (t < 64) {
        int ei = e0 + t;
        if (ei < nE) { int p = perm[ei]; sdst[t] = dst[p]; sdegs[t] = deg[p]; }
        else { sdst[t] = -1; sdegs[t] = 0.f; }
    }
    {
        int e = t >> 2, sub = t & 3;
        int ei = e0 + e;
        bool ok = ei < nE;
        int p = ok ? perm[ei] : 0;
        const float* Erow = E + (size_t)(ok ? src[p] : 0) * 128;
        const float* Rrow = R + (size_t)(ok ? rel[p] : 0) * 128;
        for (int cc = 0; cc < 4; ++cc) {
            int chunk = sub * 4 + cc;
            U8 H, L;
            if (ok) {
                float4 a0 = *(const float4*)(Erow + chunk * 8);
                float4 a1 = *(const float4*)(Erow + chunk * 8 + 4);
                float4 b0 = *(const float4*)(Rrow + chunk * 8);
                float4 b1 = *(const float4*)(Rrow + chunk * 8 + 4);
                float m[8] = {a0.x * b0.x, a0.y * b0.y, a0.z * b0.z, a0.w * b0.w,
                              a1.x * b1.x, a1.y * b1.y, a1.z * b1.z, a1.w * b1.w};
#pragma unroll
                for (int j = 0; j < 8; ++j) {
                    unsigned short h = f2bf(m[j]);
                    H.u[j] = h; L.u[j] = f2bf(m[j] - bf2f(h));
                }
            } else {
#pragma unroll
                for (int j = 0; j < 8; ++j) { H.u[j] = 0; L.u[j] = 0; }
            }
            int sc = chunk ^ (e & 7);
            *reinterpret_cast<short8*>(&msgb[0][e][sc * 8]) = H.v;
            *reinterpret_cast<short8*>(&msgb[1][e][sc * 8]) = L.v;
        }
    }
    __syncthreads();

    int w = t >> 6, l = t & 63;
    int lrow = l & 15, lk = l >> 4;
    int colbase = w * 64;
    floatx4 acc[4][4];
#pragma unroll
    for (int mt = 0; mt < 4; ++mt)
#pragma unroll
        for (int n = 0; n < 4; ++n) acc[mt][n] = (floatx4){0.f, 0.f, 0.f, 0.f};

    for (int ks = 0; ks < 4; ++ks) {
        short8 ah[4], al[4];
#pragma unroll
        for (int mt = 0; mt < 4; ++mt) {
            int row = mt * 16 + lrow;
            int sc = (ks * 4 + lk) ^ (row & 7);
            ah[mt] = *reinterpret_cast<const short8*>(&msgb[0][row][sc * 8]);
            al[mt] = *reinterpret_cast<const short8*>(&msgb[1][row][sc * 8]);
        }
#pragma unroll
        for (int ntl = 0; ntl < 4; ++ntl) {
            int ntg = w * 4 + ntl;
            size_t bo = ((size_t)(ntg * 4 + ks) * 64 + l) * 8;
            short8 bh = *reinterpret_cast<const short8*>(Bhi + bo);
            short8 bl = *reinterpret_cast<const short8*>(Blo + bo);
#pragma unroll
            for (int mt = 0; mt < 4; ++mt) {
                acc[mt][ntl] = __builtin_amdgcn_mfma_f32_16x16x32_bf16(ah[mt], bh, acc[mt][ntl], 0, 0, 0);
                acc[mt][ntl] = __builtin_amdgcn_mfma_f32_16x16x32_bf16(al[mt], bh, acc[mt][ntl], 0, 0, 0);
                acc[mt][ntl] = __builtin_amdgcn_mfma_f32_16x16x32_bf16(ah[mt], bl, acc[mt][ntl], 0, 0, 0);
            }
        }
    }
    __syncthreads();   // all LDS A-reads done; safe to overwrite msgb with V

    float* Vlds = (float*)msgb;
#pragma unroll
    for (int mt = 0; mt < 4; ++mt)
#pragma unroll
        for (int ntl = 0; ntl < 4; ++ntl) {
            int col = colbase + ntl * 16 + lrow;
#pragma unroll
            for (int r = 0; r < 4; ++r) {
                int row = mt * 16 + lk * 4 + r;
                int key = ((row >> 2) & 3) << 4;
                float vvv = acc[mt][ntl][r];
                if (col < 128) Kb[row][col ^ key] = f2bf(vvv);
                else Vlds[row * 128 + ((col - 128) ^ key)] = vvv;
            }
        }
    __syncthreads();

    // alpha: 4 threads per edge, 2 heads each
    {
        int e = t >> 2, h2 = (t & 3) * 2;
        int dn = sdst[e];
        int key = ((e >> 2) & 3) << 4;
#pragma unroll
        for (int hh = 0; hh < 2; ++hh) {
            int h = h2 + hh;
            float wgt = 0.f;
            if (dn >= 0) {
                int cb = (h * 16) ^ key;
                U8 k0, k1, q0, q1;
                k0.v = *reinterpret_cast<const short8*>(&Kb[e][cb]);
                k1.v = *reinterpret_cast<const short8*>(&Kb[e][cb + 8]);
                const unsigned short* qrow = qp + (size_t)dn * 128 + h * 16;
                q0.v = *reinterpret_cast<const short8*>(qrow);
                q1.v = *reinterpret_cast<const short8*>(qrow + 8);
                float a = 0.f;
#pragma unroll
                for (int j = 0; j < 8; ++j) {
                    a = fmaf(bf2f(k0.u[j]), bf2f(q0.u[j]), a);
                    a = fmaf(bf2f(k1.u[j]), bf2f(q1.u[j]), a);
                }
                float alpha = a * 0.25f;   // / sqrt(16)
                wgt = 1.f / (1.f + __expf(-alpha));
            }
            alph[e][h] = wgt;
        }
    }
    __syncthreads();

    // stats: column-parallel segmented reduce; thread = (col, half)
    {
        int col = t & 127, seg = t >> 7;
        int eb = seg * 32, ee = eb + 32;
        float s = 0.f, q2 = 0.f, mx = 0.f, mn = 0.f;
        int run = -1;
        for (int e = eb; e < ee; ++e) {
            int dnv = sdst[e];
            if (dnv < 0) {
                if (run >= 0) { flush1(sum, sumsq, mxe, mne, run, col, s, q2, mx, mn); run = -1; }
                continue;
            }
            int key = ((e >> 2) & 3) << 4;
            float x = Vlds[e * 128 + (col ^ key)] * alph[e][col >> 4] * sdegs[e];
            if (dnv != run) {
                if (run >= 0) flush1(sum, sumsq, mxe, mne, run, col, s, q2, mx, mn);
                run = dnv;
                s = x; q2 = x * x; mx = x; mn = x;
            } else {
                s += x; q2 = fmaf(x, x, q2);
                mx = fmaxf(mx, x); mn = fminf(mn, x);
            }
        }
        if (run >= 0) flush1(sum, sumsq, mxe, mne, run, col, s, q2, mx, mn);
    }
}

// ---------------- finalize via MFMA: 32 nodes / 256-thread block ----------------

__global__ __launch_bounds__(256, 2) void finalize_mfma(
        const float* __restrict__ sum, const float* __restrict__ sumsq,
        const unsigned* __restrict__ mxe, const unsigned* __restrict__ mne,
        const int* __restrict__ cnt, const unsigned short* __restrict__ Wop,
        const float* __restrict__ q, const float* __restrict__ ln_g,
        const float* __restrict__ ln_b, float* __restrict__ out, int nNodes) {
    __shared__ __align__(16) unsigned short aggb[32][512];   // 32KB; first 16KB reused as h[32][128] f32
    int t = threadIdx.x;
    int n0 = blockIdx.x * 32;
    {
        int nl = t >> 3, part = t & 7;
        int node = n0 + nl;
        int c0 = part * 16;
        U8 Mh[2], Xh[2], Nh[2], Sh[2];
        if (node < nNodes) {
            int c = cnt[node];
            float invc = (c > 0) ? 1.f / (float)c : 0.f;
            size_t b0 = (size_t)node * 128 + c0;
#pragma unroll
            for (int g = 0; g < 2; ++g) {
                float4 s0 = *(const float4*)(sum + b0 + g * 8);
                float4 s1 = *(const float4*)(sum + b0 + g * 8 + 4);
                float4 t0 = *(const float4*)(sumsq + b0 + g * 8);
                float4 t1 = *(const float4*)(sumsq + b0 + g * 8 + 4);
                uint4 x0 = *(const uint4*)(mxe + b0 + g * 8);
                uint4 x1 = *(const uint4*)(mxe + b0 + g * 8 + 4);
                uint4 m0 = *(const uint4*)(mne + b0 + g * 8);
                uint4 m1 = *(const uint4*)(mne + b0 + g * 8 + 4);
                float ss[8] = {s0.x, s0.y, s0.z, s0.w, s1.x, s1.y, s1.z, s1.w};
                float qq[8] = {t0.x, t0.y, t0.z, t0.w, t1.x, t1.y, t1.z, t1.w};
                unsigned xx[8] = {x0.x, x0.y, x0.z, x0.w, x1.x, x1.y, x1.z, x1.w};
                unsigned nn[8] = {m0.x, m0.y, m0.z, m0.w, m1.x, m1.y, m1.z, m1.w};
#pragma unroll
                for (int j = 0; j < 8; ++j) {
                    float s = ss[j];
                    float mean = s * invc;
                    float mxv = (c > 0) ? dec_f(xx[j]) : 0.f;
                    float mnv = (c > 0) ? dec_f(nn[j]) : 0.f;
                    float sd = sqrtf(fmaxf(qq[j] - s * s, 1e-8f));
                    Mh[g].u[j] = f2bf(mean);
                    Xh[g].u[j] = f2bf(mxv);
                    Nh[g].u[j] = f2bf(mnv);
                    Sh[g].u[j] = f2bf(sd);
                }
            }
        } else {
#pragma unroll
            for (int g = 0; g < 2; ++g)
#pragma unroll
                for (int j = 0; j < 8; ++j) { Mh[g].u[j] = 0; Xh[g].u[j] = 0; Nh[g].u[j] = 0; Sh[g].u[j] = 0; }
        }
#pragma unroll
        for (int g = 0; g < 2; ++g) {
            int base = part * 2 + g, k = nl & 7, ch;
            ch = (0 * 16 + base) ^ k; *reinterpret_cast<short8*>(&aggb[nl][ch * 8]) = Mh[g].v;
            ch = (1 * 16 + base) ^ k; *reinterpret_cast<short8*>(&aggb[nl][ch * 8]) = Xh[g].v;
            ch = (2 * 16 + base) ^ k; *reinterpret_cast<short8*>(&aggb[nl][ch * 8]) = Nh[g].v;
            ch = (3 * 16 + base) ^ k; *reinterpret_cast<short8*>(&aggb[nl][ch * 8]) = Sh[g].v;
        }
    }
    __syncthreads();

    int w = t >> 6, l = t & 63;
    int lrow = l & 15, lk = l >> 4;
    floatx4 acc[2][2];
#pragma unroll
    for (int mt = 0; mt < 2; ++mt)
#pragma unroll
        for (int n = 0; n < 2; ++n) acc[mt][n] = (floatx4){0.f, 0.f, 0.f, 0.f};
    for (int ks = 0; ks < 16; ++ks) {
        short8 a[2];
#pragma unroll
        for (int mt = 0; mt < 2; ++mt) {
            int row = mt * 16 + lrow;
            int ch = (ks * 4 + lk) ^ (row & 7);
            a[mt] = *reinterpret_cast<const short8*>(&aggb[row][ch * 8]);
        }
#pragma unroll
        for (int ntl = 0; ntl < 2; ++ntl) {
            int ntg = w * 2 + ntl;
            short8 b = *reinterpret_cast<const short8*>(Wop + ((size_t)(ntg * 16 + ks) * 64 + l) * 8);
#pragma unroll
            for (int mt = 0; mt < 2; ++mt)
                acc[mt][ntl] = __builtin_amdgcn_mfma_f32_16x16x32_bf16(a[mt], b, acc[mt][ntl], 0, 0, 0);
        }
    }
    __syncthreads();   // aggb A-reads done

    float* hb = (float*)aggb;   // [32][128]
#pragma unroll
    for (int mt = 0; mt < 2; ++mt)
#pragma unroll
        for (int ntl = 0; ntl < 2; ++ntl) {
            int col = (w * 2 + ntl) * 16 + lrow;
#pragma unroll
            for (int r = 0; r < 4; ++r) {
                int row = mt * 16 + lk * 4 + r;
                int node = n0 + row;
                float h = acc[mt][ntl][r] + ((node < nNodes) ? q[(size_t)node * 128 + col] : 0.f);
                int key = ((row >> 2) & 3) << 4;
                hb[row * 128 + (col ^ key)] = h;
            }
        }
    __syncthreads();

    {
        int nl = t >> 3, part = t & 7;
        int node = n0 + nl;
        int key = ((nl >> 2) & 3) << 4;
        int c0 = part * 16;
        int cb = c0 ^ key;
        const float* hrow = hb + nl * 128;
        float4 h0 = *(const float4*)(hrow + cb);
        float4 h1 = *(const float4*)(hrow + cb + 4);
        float4 h2 = *(const float4*)(hrow + cb + 8);
        float4 h3 = *(const float4*)(hrow + cb + 12);
        float ps = h0.x + h0.y + h0.z + h0.w + h1.x + h1.y + h1.z + h1.w
                 + h2.x + h2.y + h2.z + h2.w + h3.x + h3.y + h3.z + h3.w;
        ps += __shfl_xor(ps, 1);
        ps += __shfl_xor(ps, 2);
        ps += __shfl_xor(ps, 4);
        float mu = ps * (1.f / 128.f);
        float d0x = h0.x - mu, d0y = h0.y - mu, d0z = h0.z - mu, d0w = h0.w - mu;
        float d1x = h1.x - mu, d1y = h1.y - mu, d1z = h1.z - mu, d1w = h1.w - mu;
        float d2x = h2.x - mu, d2y = h2.y - mu, d2z = h2.z - mu, d2w = h2.w - mu;
        float d3x = h3.x - mu, d3y = h3.y - mu, d3z = h3.z - mu, d3w = h3.w - mu;
        float pv = d0x*d0x + d0y*d0y + d0z*d0z + d0w*d0w
                 + d1x*d1x + d1y*d1y + d1z*d1z + d1w*d1w
                 + d2x*d2x + d2y*d2y + d2z*d2z + d2w*d2w
                 + d3x*d3x + d3y*d3y + d3z*d3z + d3w*d3w;
        pv += __shfl_xor(pv, 1);
        pv += __shfl_xor(pv, 2);
        pv += __shfl_xor(pv, 4);
        float rr = rsqrtf(pv * (1.f / 128.f) + 1e-5f);
        if (node < nNodes) {
            float4 g0 = *(const float4*)(ln_g + c0);
            float4 g1 = *(const float4*)(ln_g + c0 + 4);
            float4 g2 = *(const float4*)(ln_g + c0 + 8);
            float4 g3 = *(const float4*)(ln_g + c0 + 12);
            float4 b0 = *(const float4*)(ln_b + c0);
            float4 b1 = *(const float4*)(ln_b + c0 + 4);
            float4 b2 = *(const float4*)(ln_b + c0 + 8);
            float4 b3 = *(const float4*)(ln_b + c0 + 12);
            float* orow = out + (size_t)node * 128 + c0;
            float4 o;
            o.x = d0x * rr * g0.x + b0.x; o.y = d0y * rr * g0.y + b0.y;
            o.z = d0z * rr * g0.z + b0.z; o.w = d0w * rr * g0.w + b0.w;
            *(float4*)(orow) = o;
            o.x = d1x * rr * g1.x + b1.x; o.y = d1y * rr * g1.y + b1.y;
            o.z = d1z * rr * g1.z + b1.z; o.w = d1w * rr * g1.w + b1.w;
            *(float4*)(orow + 4) = o;
            o.x = d2x * rr * g2.x + b2.x; o.y = d2y * rr * g2.y + b2.y;
            o.z = d2z * rr * g2.z + b2.z; o.w = d2w * rr * g2.w + b2.w;
            *(float4*)(orow + 8) = o;
            o.x = d3x * rr * g3.x + b3.x; o.y = d3y * rr * g3.y + b3.y;
            o.z = d3z * rr * g3.z + b3.z; o.w = d3w * rr * g3.w + b3.w;
            *(float4*)(orow + 12) = o;
        }
    }
}

// ---------------- launch ----------------

extern "C" void kernel_launch(void* const* d_in, const int* in_sizes, int n_in,
                              void* d_out, int out_size, void* d_ws, size_t ws_size,
                              hipStream_t stream) {
    const float* q    = (const float*)d_in[0];
    const float* E    = (const float*)d_in[1];
    const float* R    = (const float*)d_in[2];
    const float* Wq   = (const float*)d_in[3];
    const float* Wk   = (const float*)d_in[4];
    const float* Wv   = (const float*)d_in[5];
    const float* Wo   = (const float*)d_in[6];
    const float* ln_g = (const float*)d_in[7];
    const float* ln_b = (const float*)d_in[8];
    const float* deg  = (const float*)d_in[9];
    const int* src    = (const int*)d_in[10];
    const int* rel    = (const int*)d_in[11];
    const int* dst    = (const int*)d_in[12];
    int nNodes = in_sizes[0] / D;   // 50000
    int nEdges = in_sizes[10];      // 500000
    float* out = (float*)d_out;

    char* w = (char*)d_ws;
    size_t nd = (size_t)nNodes * D;
    float* sum    = (float*)w;               w += nd * 4;
    float* sumsq  = (float*)w;               w += nd * 4;
    unsigned* mxe = (unsigned*)w;            w += nd * 4;
    unsigned* mne = (unsigned*)w;            w += nd * 4;
    unsigned short* qp = (unsigned short*)w; w += nd * 2;
    int* cnt      = (int*)w;                 w += (size_t)nNodes * 4;
    int* off      = (int*)w;                 w += (size_t)nNodes * 4;
    int* fill     = (int*)w;                 w += (size_t)nNodes * 4;
    int* perm     = (int*)w;                 w += (size_t)nEdges * 4;
    int* chunksum = (int*)w;                 w += 256 * 4;
    int* chunkoff = (int*)w;                 w += 256 * 4;
    unsigned short* Wp_hi  = (unsigned short*)w; w += 16 * 4 * 64 * 8 * 2;   // 64KB
    unsigned short* Wp_lo  = (unsigned short*)w; w += 16 * 4 * 64 * 8 * 2;
    unsigned short* Wqp_hi = (unsigned short*)w; w += 8 * 4 * 64 * 8 * 2;    // 32KB
    unsigned short* Wqp_lo = (unsigned short*)w; w += 8 * 4 * 64 * 8 * 2;
    unsigned short* Wop    = (unsigned short*)w; w += 8 * 16 * 64 * 8 * 2;   // 128KB
    // total ~118 MB

    int nChunks = (nNodes + 255) / 256;

    init_kernel<<<(int)((nd + 255) / 256), 256, 0, stream>>>(sum, sumsq, mxe, mne, cnt, fill, nNodes);
    hist_kernel<<<(nEdges + 255) / 256, 256, 0, stream>>>(dst, cnt, nEdges);
    scanA_kernel<<<nChunks, 256, 0, stream>>>(cnt, chunksum, nNodes);
    scanB_kernel<<<1, 256, 0, stream>>>(chunksum, chunkoff, nChunks);
    scanC_kernel<<<nChunks, 256, 0, stream>>>(cnt, chunkoff, off, nNodes);
    scatter_kernel<<<(nEdges + 255) / 256, 256, 0, stream>>>(dst, off, fill, perm, nEdges);

    pack_kernel<<<16 * 4, 64, 0, stream>>>(Wk, Wv, 128, Wp_hi, Wp_lo);
    pack_kernel<<<8 * 4, 64, 0, stream>>>(Wq, Wq, 128, Wqp_hi, Wqp_lo);
    pack_kernel<<<8 * 16, 64, 0, stream>>>(Wo, Wo, 512, Wop, (unsigned short*)nullptr);

    qproj_mfma<<<(nNodes + 63) / 64, 256, 0, stream>>>(q, Wqp_hi, Wqp_lo, qp, nNodes);
    edge_mfma<<<(nEdges + 63) / 64, 256, 0, stream>>>(E, R, qp, Wp_hi, Wp_lo, deg,
                                                      src, rel, dst, perm,
                                                      sum, sumsq, mxe, mne, nEdges);
    finalize_mfma<<<(nNodes + 31) / 32, 256, 0, stream>>>(sum, sumsq, mxe, mne, cnt, Wop,
                                                          q, ln_g, ln_b, out, nNodes);
}